// Round 8
// baseline (188.122 us; speedup 1.0000x reference)
//
#include <hip/hip_runtime.h>
#include <math.h>

namespace {

constexpr int NN = 20000;   // nodes
constexpr int NE = 400000;  // edges

constexpr float RS8   = 0.35355339059327373f;  // 1/sqrt(8)
constexpr float RS128 = 0.08838834764831845f;  // 1/sqrt(128)

constexpr int BSTRIDE = 32;   // blob floats/slot (128B line): [0..3]=hk bf16x2, [4..7]=ea, [8..23]=v, [24]=src

__device__ __forceinline__ float silu_f(float x) {
    return x / (1.0f + __expf(-x));
}

// pack two floats as bf16 pair (RNE) into one uint
__device__ __forceinline__ unsigned int bf2(float a, float b) {
    unsigned int ua = __float_as_uint(a), ub = __float_as_uint(b);
    ua = (ua + 0x7FFFu + ((ua >> 16) & 1u)) >> 16;
    ub = (ub + 0x7FFFu + ((ub >> 16) & 1u)) >> 16;
    return (ub << 16) | ua;
}
__device__ __forceinline__ float bflo(unsigned int u) { return __uint_as_float(u << 16); }
__device__ __forceinline__ float bfhi(unsigned int u) { return __uint_as_float(u & 0xFFFF0000u); }

// ---------------- node + hist kernel: sc, nf, qk, counts ----------------
__global__ __launch_bounds__(256) void node_hist_kernel(
    const float* __restrict__ node_input, const float* __restrict__ node_attr,
    const int* __restrict__ edge_dst,
    const float* __restrict__ W_sc, const float* __restrict__ W_lin1,
    const float* __restrict__ W_hq, const float* __restrict__ W_dot,
    float* __restrict__ nf_out, float* __restrict__ qk_out, float* __restrict__ sc_out,
    int* __restrict__ counts)
{
    // histogram part (all blocks)
    int e = blockIdx.x * 256 + threadIdx.x;
    if (e < NE) atomicAdd(&counts[edge_dst[e]], 1);

    // node part (first 79 blocks only)
    if (blockIdx.x >= (NN + 255) / 256) return;

    __shared__ float sWsc[2048];   // [a][b][c] (16,8,16), scale folded
    __shared__ float sW1[256];     // [a][c] (16,16)
    __shared__ float sWq[128];     // [a][c] (16,8)
    __shared__ float sdot[64];     // [a][c] (8,8)
    for (int i = threadIdx.x; i < 2048; i += 256) sWsc[i] = W_sc[i] * RS128;
    if (threadIdx.x < 256) sW1[threadIdx.x] = W_lin1[threadIdx.x] * 0.25f;
    if (threadIdx.x < 128) sWq[threadIdx.x] = W_hq[threadIdx.x] * 0.25f;
    if (threadIdx.x < 64)  sdot[threadIdx.x] = W_dot[threadIdx.x] * 0.125f;  // 1/sqrt(64)
    __syncthreads();

    int n = blockIdx.x * 256 + threadIdx.x;
    if (n >= NN) return;

    float ni[16], na[8];
    {
        const float4* p = (const float4*)(node_input + (size_t)n * 16);
        #pragma unroll
        for (int j = 0; j < 4; ++j) {
            float4 t = p[j];
            ni[4*j+0]=t.x; ni[4*j+1]=t.y; ni[4*j+2]=t.z; ni[4*j+3]=t.w;
        }
        const float4* pa = (const float4*)(node_attr + (size_t)n * 8);
        #pragma unroll
        for (int j = 0; j < 2; ++j) {
            float4 t = pa[j];
            na[4*j+0]=t.x; na[4*j+1]=t.y; na[4*j+2]=t.z; na[4*j+3]=t.w;
        }
    }

    float sc[16];
    #pragma unroll
    for (int c = 0; c < 16; ++c) sc[c] = 0.f;
    #pragma unroll 4
    for (int a = 0; a < 16; ++a) {
        #pragma unroll
        for (int b = 0; b < 8; ++b) {
            float p = ni[a] * na[b];
            const float* w = &sWsc[(a * 8 + b) * 16];
            #pragma unroll
            for (int c = 0; c < 16; ++c) sc[c] += p * w[c];
        }
    }

    float nf[16];
    #pragma unroll
    for (int c = 0; c < 16; ++c) {
        float t = 0.f;
        #pragma unroll
        for (int a = 0; a < 16; ++a) t += ni[a] * sW1[a * 16 + c];
        nf[c] = t;
    }
    float q[8];
    #pragma unroll
    for (int c = 0; c < 8; ++c) {
        float t = 0.f;
        #pragma unroll
        for (int a = 0; a < 16; ++a) t += nf[a] * sWq[a * 8 + c];
        q[c] = t;
    }
    float qk[8];
    #pragma unroll
    for (int c = 0; c < 8; ++c) {
        float t = 0.f;
        #pragma unroll
        for (int a = 0; a < 8; ++a) t += q[a] * sdot[a * 8 + c];
        qk[c] = t;
    }

    float4* nfo = (float4*)(nf_out + (size_t)n * 16);
    #pragma unroll
    for (int j = 0; j < 4; ++j) nfo[j] = make_float4(nf[4*j], nf[4*j+1], nf[4*j+2], nf[4*j+3]);
    float4* qko = (float4*)(qk_out + (size_t)n * 8);
    #pragma unroll
    for (int j = 0; j < 2; ++j) qko[j] = make_float4(qk[4*j], qk[4*j+1], qk[4*j+2], qk[4*j+3]);
    float4* sco = (float4*)(sc_out + (size_t)n * 16);
    #pragma unroll
    for (int j = 0; j < 4; ++j) sco[j] = make_float4(sc[4*j], sc[4*j+1], sc[4*j+2], sc[4*j+3]);
}

// ---------------- scan: exclusive prefix of counts -> offs ----------------
__global__ __launch_bounds__(1024) void scan_kernel(
    const int* __restrict__ counts, int* __restrict__ offs)
{
    __shared__ int part[1024];
    int t = threadIdx.x;
    int base = t * 20;
    int s = 0;
    #pragma unroll 4
    for (int i = 0; i < 20; ++i) {
        int idx = base + i;
        if (idx < NN) s += counts[idx];
    }
    part[t] = s;
    __syncthreads();
    #pragma unroll
    for (int d = 1; d < 1024; d <<= 1) {
        int v = (t >= d) ? part[t - d] : 0;
        __syncthreads();
        part[t] += v;
        __syncthreads();
    }
    int run = part[t] - s;
    for (int i = 0; i < 20; ++i) {
        int idx = base + i;
        if (idx < NN) {
            offs[idx] = run;
            run += counts[idx];
        }
    }
}

// ---------------- MLP hiddens with transposed weights ----------------
__device__ __forceinline__ void mlp_hidden_t(const float es[16], const float* __restrict__ w0t,
                                             const float* __restrict__ w1t, const float* __restrict__ w2t,
                                             float out[8])
{
    float h0[8];
    #pragma unroll
    for (int j = 0; j < 8; ++j) {
        float t = 0.f;
        #pragma unroll
        for (int i = 0; i < 16; ++i) t += es[i] * w0t[j * 16 + i];
        h0[j] = silu_f(t);
    }
    float h1[8];
    #pragma unroll
    for (int j = 0; j < 8; ++j) {
        float t = 0.f;
        #pragma unroll
        for (int i = 0; i < 8; ++i) t += h0[i] * w1t[j * 8 + i];
        h1[j] = silu_f(t);
    }
    #pragma unroll
    for (int j = 0; j < 8; ++j) {
        float t = 0.f;
        #pragma unroll
        for (int i = 0; i < 8; ++i) t += h1[i] * w2t[j * 8 + i];
        out[j] = silu_f(t);
    }
}

// ---------------- A: MLP + v + slot placement (natural edge order, coalesced reads) ----------------
__global__ __launch_bounds__(256) void edge_mlp_kernel(
    const int* __restrict__ edge_src, const int* __restrict__ edge_dst,
    const float* __restrict__ edge_attr, const float* __restrict__ edge_scalars,
    const float* __restrict__ nf,
    const float* __restrict__ fck_w0, const float* __restrict__ fck_w1,
    const float* __restrict__ fck_w2,
    const float* __restrict__ fcv_w0, const float* __restrict__ fcv_w1,
    const float* __restrict__ fcv_w2, const float* __restrict__ fcv_w3,
    int* __restrict__ offs,            // exclusive -> inclusive via atomics (fused place)
    float* __restrict__ blob)
{
    __shared__ float sk0t[128], sk1t[64], sk2t[64];
    __shared__ float sv0t[128], sv1t[64], sv2t[64], sv3t[512];
    int tid = threadIdx.x;
    for (int i = tid; i < 128; i += 256) { int r = i >> 3, c = i & 7; sk0t[c*16+r] = fck_w0[i] * 0.25f; }
    for (int i = tid; i < 64;  i += 256) { int r = i >> 3, c = i & 7; sk1t[c*8+r]  = fck_w1[i] * RS8; }
    for (int i = tid; i < 64;  i += 256) { int r = i >> 3, c = i & 7; sk2t[c*8+r]  = fck_w2[i] * RS8; }
    for (int i = tid; i < 128; i += 256) { int r = i >> 3, c = i & 7; sv0t[c*16+r] = fcv_w0[i] * 0.25f; }
    for (int i = tid; i < 64;  i += 256) { int r = i >> 3, c = i & 7; sv1t[c*8+r]  = fcv_w1[i] * RS8; }
    for (int i = tid; i < 64;  i += 256) { int r = i >> 3, c = i & 7; sv2t[c*8+r]  = fcv_w2[i] * RS8; }
    for (int i = tid; i < 512; i += 256) {
        int h = i >> 6, u = (i >> 2) & 15, w = i & 3;
        sv3t[u * 32 + h * 4 + w] = fcv_w3[i] * (RS8 * 0.5f);  // * 1/sqrt(4)
    }
    __syncthreads();

    int e = blockIdx.x * 256 + tid;
    if (e >= NE) return;

    int dst = edge_dst[e];
    int slot = atomicAdd(&offs[dst], 1);   // fused place; latency overlaps MLP below
    int src = edge_src[e];

    float es[16];
    {
        const float4* p = (const float4*)(edge_scalars + (size_t)e * 16);
        #pragma unroll
        for (int j = 0; j < 4; ++j) {
            float4 t = p[j];
            es[4*j+0]=t.x; es[4*j+1]=t.y; es[4*j+2]=t.z; es[4*j+3]=t.w;
        }
    }

    float hk[8], hv[8];
    mlp_hidden_t(es, sk0t, sk1t, sk2t, hk);
    mlp_hidden_t(es, sv0t, sv1t, sv2t, hv);

    float4 ea = *(const float4*)(edge_attr + (size_t)e * 4);
    float ea4[4] = {ea.x, ea.y, ea.z, ea.w};

    float sf[16];
    {
        const float4* p = (const float4*)(nf + (size_t)src * 16);
        #pragma unroll
        for (int j = 0; j < 4; ++j) {
            float4 t = p[j];
            sf[4*j+0]=t.x; sf[4*j+1]=t.y; sf[4*j+2]=t.z; sf[4*j+3]=t.w;
        }
    }

    float* bp = blob + (size_t)slot * BSTRIDE;

    uint4 hku = make_uint4(bf2(hk[0],hk[1]), bf2(hk[2],hk[3]), bf2(hk[4],hk[5]), bf2(hk[6],hk[7]));
    *(uint4*)(bp + 0) = hku;
    *(float4*)(bp + 4) = ea;

    // v[u] = sf[u] * sum_h hv[h] * dot(ea, sv3t[u][h][:])  -> blob[8..23]
    #pragma unroll
    for (int j = 0; j < 4; ++j) {
        float o[4];
        #pragma unroll
        for (int cc = 0; cc < 4; ++cc) {
            int u = 4*j + cc;
            float t = 0.f;
            #pragma unroll
            for (int h = 0; h < 8; ++h) {
                const float4 r = *(const float4*)(&sv3t[u * 32 + h * 4]);
                t += hv[h] * (ea4[0]*r.x + ea4[1]*r.y + ea4[2]*r.z + ea4[3]*r.w);
            }
            o[cc] = sf[u] * t;
        }
        *(float4*)(bp + 8 + 4*j) = make_float4(o[0], o[1], o[2], o[3]);
    }
    bp[24] = __int_as_float(src);
}

// ---------------- B: fused logit + softmax-gather + output ----------------
// 256-thread block = 16 nodes; 16-lane group g of wave w owns node nbase + w*4 + g.
// Per edge: lane u computes the u-slice of the logit from LDS R (static ln),
// 4-step DPP shfl_xor reduce within the group, exp, coalesced v-accumulate.
constexpr int GN = 16;         // nodes per block
constexpr int RSTRIDE = 516;   // 512 + 4 pad (spreads node bases across banks)

__global__ __launch_bounds__(256) void fused_gather_kernel(
    const int* __restrict__ offs,
    const float* __restrict__ blob,
    const float* __restrict__ nf, const float* __restrict__ qk,
    const float* __restrict__ fck_w3,
    const float* __restrict__ sc, const float* __restrict__ W_lin2,
    float* __restrict__ out)
{
    __shared__ float R[GN * RSTRIDE];   // 33 KB
    int tid = threadIdx.x;
    int nbase = blockIdx.x * GN;        // NN = 1250*16

    // block-cooperative R build: R[ln][h*64+u*4+v] = S3 * sum_c W3[h,u,v,c]*qk[n][c]
    constexpr float S3 = RS8 * 0.125f;  // fck_w3 scale * 1/sqrt(64)
    for (int idx = tid; idx < GN * 512; idx += 256) {
        int ln = idx >> 9;
        int j = idx & 511;              // j = h*64 + u*4 + v
        int h = j >> 6, uv = j & 63;
        const float4* w = (const float4*)(fck_w3 + h * 512 + uv * 8);
        float4 w0 = w[0], w1 = w[1];
        const float4* qp = (const float4*)(qk + (size_t)(nbase + ln) * 8);
        float4 q0 = qp[0], q1 = qp[1];
        float t = w0.x*q0.x + w0.y*q0.y + w0.z*q0.z + w0.w*q0.w
                + w1.x*q1.x + w1.y*q1.y + w1.z*q1.z + w1.w*q1.w;
        R[ln * RSTRIDE + j] = t * S3;
    }
    __syncthreads();

    int w = tid >> 6;
    int L = tid & 63;
    int g = L >> 4;
    int u = L & 15;
    int ln = w * 4 + g;
    int n = nbase + ln;

    int gs = (n == 0) ? 0 : offs[n - 1];
    int ge = offs[n];

    const float* Rb = &R[ln * RSTRIDE];
    float accv = 0.f, accz = 0.f;
    for (int j = gs; j < ge; ++j) {
        const float* bp = blob + (size_t)j * BSTRIDE;
        uint4 hku = *(const uint4*)(bp + 0);          // group-broadcast
        float4 ea = *(const float4*)(bp + 4);         // group-broadcast
        int src = __float_as_int(bp[24]);             // group-broadcast
        float sfu = nf[(size_t)src * 16 + u];         // 64B coalesced per group

        float hk[8];
        hk[0]=bflo(hku.x); hk[1]=bfhi(hku.x); hk[2]=bflo(hku.y); hk[3]=bfhi(hku.y);
        hk[4]=bflo(hku.z); hk[5]=bfhi(hku.z); hk[6]=bflo(hku.w); hk[7]=bfhi(hku.w);

        float xu = 0.f;
        #pragma unroll
        for (int h = 0; h < 8; ++h) {
            const float4 r = *(const float4*)(Rb + h * 64 + u * 4);
            xu += hk[h] * (ea.x*r.x + ea.y*r.y + ea.z*r.z + ea.w*r.w);
        }
        float px = sfu * xu;
        // 4-step reduce within the 16-lane group (xor 1,2,4,8 stay in-group)
        px += __shfl_xor(px, 1);
        px += __shfl_xor(px, 2);
        px += __shfl_xor(px, 4);
        px += __shfl_xor(px, 8);

        float exv = __expf(px);
        accz += exv;                                  // identical across the group
        accv += exv * bp[8 + u];                      // 64B coalesced per group
    }

    float den = (accz == 0.f) ? 1.f : accz;
    float a = 0.25f * accv / den;                     // fold W_lin2's 1/sqrt(16)

    // epilogue: out[n][u] = sc[n][u] + sum_uu a[uu] * W_lin2[uu][u]
    float t = sc[(size_t)n * 16 + u];
    #pragma unroll
    for (int uu = 0; uu < 16; ++uu) {
        float au = __shfl(a, g * 16 + uu);
        t += au * W_lin2[uu * 16 + u];                // 1 KB table, L1-resident
    }
    out[(size_t)n * 16 + u] = t;
}

} // namespace

extern "C" void kernel_launch(void* const* d_in, const int* in_sizes, int n_in,
                              void* d_out, int out_size, void* d_ws, size_t ws_size,
                              hipStream_t stream)
{
    const float* node_input   = (const float*)d_in[0];
    const float* node_attr    = (const float*)d_in[1];
    const int*   edge_src     = (const int*)d_in[2];
    const int*   edge_dst     = (const int*)d_in[3];
    const float* edge_attr    = (const float*)d_in[4];
    const float* edge_scalars = (const float*)d_in[5];
    const float* W_sc   = (const float*)d_in[6];
    const float* W_lin1 = (const float*)d_in[7];
    const float* W_hq   = (const float*)d_in[8];
    const float* fck_w0 = (const float*)d_in[9];
    const float* fck_w1 = (const float*)d_in[10];
    const float* fck_w2 = (const float*)d_in[11];
    const float* fck_w3 = (const float*)d_in[12];
    const float* fcv_w0 = (const float*)d_in[13];
    const float* fcv_w1 = (const float*)d_in[14];
    const float* fcv_w2 = (const float*)d_in[15];
    const float* fcv_w3 = (const float*)d_in[16];
    const float* W_dot  = (const float*)d_in[17];
    const float* W_lin2 = (const float*)d_in[18];

    float* ws  = (float*)d_ws;
    float* nf  = ws;                       // NN*16
    float* qk  = nf  + (size_t)NN * 16;    // NN*8
    float* sc  = qk  + (size_t)NN * 8;     // NN*16
    float* blob = sc + (size_t)NN * 16;    // NE*32 (hk/ea/v/src, one 128B line per slot)
    int* counts = (int*)(blob + (size_t)NE * BSTRIDE);  // NN
    int* offs   = counts + NN;                          // NN

    hipMemsetAsync(counts, 0, (size_t)NN * sizeof(int), stream);

    const int EB = (NE + 255) / 256;   // 1563
    node_hist_kernel<<<EB, 256, 0, stream>>>(
        node_input, node_attr, edge_dst, W_sc, W_lin1, W_hq, W_dot, nf, qk, sc, counts);
    scan_kernel<<<1, 1024, 0, stream>>>(counts, offs);
    edge_mlp_kernel<<<EB, 256, 0, stream>>>(
        edge_src, edge_dst, edge_attr, edge_scalars, nf,
        fck_w0, fck_w1, fck_w2, fcv_w0, fcv_w1, fcv_w2, fcv_w3, offs, blob);
    fused_gather_kernel<<<NN / GN, 256, 0, stream>>>(
        offs, blob, nf, qk, fck_w3, sc, W_lin2, (float*)d_out);
}

// Round 9
// 161.141 us; speedup vs baseline: 1.1674x; 1.1674x over previous
//
#include <hip/hip_runtime.h>
#include <math.h>

namespace {

constexpr int NN = 20000;   // nodes
constexpr int NE = 400000;  // edges

constexpr float RS8   = 0.35355339059327373f;  // 1/sqrt(8)
constexpr float RS128 = 0.08838834764831845f;  // 1/sqrt(128)

constexpr int BSTRIDE = 32;   // blob floats/slot (128B line): [0..3]=hk bf16x2, [4..7]=ea, [8..23]=v, [24]=src

__device__ __forceinline__ float silu_f(float x) {
    return x / (1.0f + __expf(-x));
}

// pack two floats as bf16 pair (RNE) into one uint
__device__ __forceinline__ unsigned int bf2(float a, float b) {
    unsigned int ua = __float_as_uint(a), ub = __float_as_uint(b);
    ua = (ua + 0x7FFFu + ((ua >> 16) & 1u)) >> 16;
    ub = (ub + 0x7FFFu + ((ub >> 16) & 1u)) >> 16;
    return (ub << 16) | ua;
}
__device__ __forceinline__ float bflo(unsigned int u) { return __uint_as_float(u << 16); }
__device__ __forceinline__ float bfhi(unsigned int u) { return __uint_as_float(u & 0xFFFF0000u); }

// ---------------- node + hist kernel: sc, nf, qk, counts ----------------
__global__ __launch_bounds__(256) void node_hist_kernel(
    const float* __restrict__ node_input, const float* __restrict__ node_attr,
    const int* __restrict__ edge_dst,
    const float* __restrict__ W_sc, const float* __restrict__ W_lin1,
    const float* __restrict__ W_hq, const float* __restrict__ W_dot,
    float* __restrict__ nf_out, float* __restrict__ qk_out, float* __restrict__ sc_out,
    int* __restrict__ counts)
{
    // histogram part (all blocks)
    int e = blockIdx.x * 256 + threadIdx.x;
    if (e < NE) atomicAdd(&counts[edge_dst[e]], 1);

    // node part (first 79 blocks only)
    if (blockIdx.x >= (NN + 255) / 256) return;

    __shared__ float sWsc[2048];   // [a][b][c] (16,8,16), scale folded
    __shared__ float sW1[256];     // [a][c] (16,16)
    __shared__ float sWq[128];     // [a][c] (16,8)
    __shared__ float sdot[64];     // [a][c] (8,8)
    for (int i = threadIdx.x; i < 2048; i += 256) sWsc[i] = W_sc[i] * RS128;
    if (threadIdx.x < 256) sW1[threadIdx.x] = W_lin1[threadIdx.x] * 0.25f;
    if (threadIdx.x < 128) sWq[threadIdx.x] = W_hq[threadIdx.x] * 0.25f;
    if (threadIdx.x < 64)  sdot[threadIdx.x] = W_dot[threadIdx.x] * 0.125f;  // 1/sqrt(64)
    __syncthreads();

    int n = blockIdx.x * 256 + threadIdx.x;
    if (n >= NN) return;

    float ni[16], na[8];
    {
        const float4* p = (const float4*)(node_input + (size_t)n * 16);
        #pragma unroll
        for (int j = 0; j < 4; ++j) {
            float4 t = p[j];
            ni[4*j+0]=t.x; ni[4*j+1]=t.y; ni[4*j+2]=t.z; ni[4*j+3]=t.w;
        }
        const float4* pa = (const float4*)(node_attr + (size_t)n * 8);
        #pragma unroll
        for (int j = 0; j < 2; ++j) {
            float4 t = pa[j];
            na[4*j+0]=t.x; na[4*j+1]=t.y; na[4*j+2]=t.z; na[4*j+3]=t.w;
        }
    }

    float sc[16];
    #pragma unroll
    for (int c = 0; c < 16; ++c) sc[c] = 0.f;
    #pragma unroll 4
    for (int a = 0; a < 16; ++a) {
        #pragma unroll
        for (int b = 0; b < 8; ++b) {
            float p = ni[a] * na[b];
            const float* w = &sWsc[(a * 8 + b) * 16];
            #pragma unroll
            for (int c = 0; c < 16; ++c) sc[c] += p * w[c];
        }
    }

    float nf[16];
    #pragma unroll
    for (int c = 0; c < 16; ++c) {
        float t = 0.f;
        #pragma unroll
        for (int a = 0; a < 16; ++a) t += ni[a] * sW1[a * 16 + c];
        nf[c] = t;
    }
    float q[8];
    #pragma unroll
    for (int c = 0; c < 8; ++c) {
        float t = 0.f;
        #pragma unroll
        for (int a = 0; a < 16; ++a) t += nf[a] * sWq[a * 8 + c];
        q[c] = t;
    }
    float qk[8];
    #pragma unroll
    for (int c = 0; c < 8; ++c) {
        float t = 0.f;
        #pragma unroll
        for (int a = 0; a < 8; ++a) t += q[a] * sdot[a * 8 + c];
        qk[c] = t;
    }

    float4* nfo = (float4*)(nf_out + (size_t)n * 16);
    #pragma unroll
    for (int j = 0; j < 4; ++j) nfo[j] = make_float4(nf[4*j], nf[4*j+1], nf[4*j+2], nf[4*j+3]);
    float4* qko = (float4*)(qk_out + (size_t)n * 8);
    #pragma unroll
    for (int j = 0; j < 2; ++j) qko[j] = make_float4(qk[4*j], qk[4*j+1], qk[4*j+2], qk[4*j+3]);
    float4* sco = (float4*)(sc_out + (size_t)n * 16);
    #pragma unroll
    for (int j = 0; j < 4; ++j) sco[j] = make_float4(sc[4*j], sc[4*j+1], sc[4*j+2], sc[4*j+3]);
}

// ---------------- scan: exclusive prefix of counts -> offs ----------------
__global__ __launch_bounds__(1024) void scan_kernel(
    const int* __restrict__ counts, int* __restrict__ offs)
{
    __shared__ int part[1024];
    int t = threadIdx.x;
    int base = t * 20;
    int s = 0;
    #pragma unroll 4
    for (int i = 0; i < 20; ++i) {
        int idx = base + i;
        if (idx < NN) s += counts[idx];
    }
    part[t] = s;
    __syncthreads();
    #pragma unroll
    for (int d = 1; d < 1024; d <<= 1) {
        int v = (t >= d) ? part[t - d] : 0;
        __syncthreads();
        part[t] += v;
        __syncthreads();
    }
    int run = part[t] - s;
    for (int i = 0; i < 20; ++i) {
        int idx = base + i;
        if (idx < NN) {
            offs[idx] = run;
            run += counts[idx];
        }
    }
}

// ---------------- MLP hiddens with transposed weights ----------------
__device__ __forceinline__ void mlp_hidden_t(const float es[16], const float* __restrict__ w0t,
                                             const float* __restrict__ w1t, const float* __restrict__ w2t,
                                             float out[8])
{
    float h0[8];
    #pragma unroll
    for (int j = 0; j < 8; ++j) {
        float t = 0.f;
        #pragma unroll
        for (int i = 0; i < 16; ++i) t += es[i] * w0t[j * 16 + i];
        h0[j] = silu_f(t);
    }
    float h1[8];
    #pragma unroll
    for (int j = 0; j < 8; ++j) {
        float t = 0.f;
        #pragma unroll
        for (int i = 0; i < 8; ++i) t += h0[i] * w1t[j * 8 + i];
        h1[j] = silu_f(t);
    }
    #pragma unroll
    for (int j = 0; j < 8; ++j) {
        float t = 0.f;
        #pragma unroll
        for (int i = 0; i < 8; ++i) t += h1[i] * w2t[j * 8 + i];
        out[j] = silu_f(t);
    }
}

// ---------------- A: MLP + v + slot placement (natural edge order, coalesced reads) ----------------
__global__ __launch_bounds__(256) void edge_mlp_kernel(
    const int* __restrict__ edge_src, const int* __restrict__ edge_dst,
    const float* __restrict__ edge_attr, const float* __restrict__ edge_scalars,
    const float* __restrict__ nf,
    const float* __restrict__ fck_w0, const float* __restrict__ fck_w1,
    const float* __restrict__ fck_w2,
    const float* __restrict__ fcv_w0, const float* __restrict__ fcv_w1,
    const float* __restrict__ fcv_w2, const float* __restrict__ fcv_w3,
    int* __restrict__ offs,            // exclusive -> inclusive via atomics (fused place)
    float* __restrict__ blob)
{
    __shared__ float sk0t[128], sk1t[64], sk2t[64];
    __shared__ float sv0t[128], sv1t[64], sv2t[64], sv3t[512];
    int tid = threadIdx.x;
    for (int i = tid; i < 128; i += 256) { int r = i >> 3, c = i & 7; sk0t[c*16+r] = fck_w0[i] * 0.25f; }
    for (int i = tid; i < 64;  i += 256) { int r = i >> 3, c = i & 7; sk1t[c*8+r]  = fck_w1[i] * RS8; }
    for (int i = tid; i < 64;  i += 256) { int r = i >> 3, c = i & 7; sk2t[c*8+r]  = fck_w2[i] * RS8; }
    for (int i = tid; i < 128; i += 256) { int r = i >> 3, c = i & 7; sv0t[c*16+r] = fcv_w0[i] * 0.25f; }
    for (int i = tid; i < 64;  i += 256) { int r = i >> 3, c = i & 7; sv1t[c*8+r]  = fcv_w1[i] * RS8; }
    for (int i = tid; i < 64;  i += 256) { int r = i >> 3, c = i & 7; sv2t[c*8+r]  = fcv_w2[i] * RS8; }
    for (int i = tid; i < 512; i += 256) {
        int h = i >> 6, u = (i >> 2) & 15, w = i & 3;
        sv3t[u * 32 + h * 4 + w] = fcv_w3[i] * (RS8 * 0.5f);  // * 1/sqrt(4)
    }
    __syncthreads();

    int e = blockIdx.x * 256 + tid;
    if (e >= NE) return;

    int dst = edge_dst[e];
    int slot = atomicAdd(&offs[dst], 1);   // fused place; latency overlaps MLP below
    int src = edge_src[e];

    float es[16];
    {
        const float4* p = (const float4*)(edge_scalars + (size_t)e * 16);
        #pragma unroll
        for (int j = 0; j < 4; ++j) {
            float4 t = p[j];
            es[4*j+0]=t.x; es[4*j+1]=t.y; es[4*j+2]=t.z; es[4*j+3]=t.w;
        }
    }

    float hk[8], hv[8];
    mlp_hidden_t(es, sk0t, sk1t, sk2t, hk);
    mlp_hidden_t(es, sv0t, sv1t, sv2t, hv);

    float4 ea = *(const float4*)(edge_attr + (size_t)e * 4);
    float ea4[4] = {ea.x, ea.y, ea.z, ea.w};

    float sf[16];
    {
        const float4* p = (const float4*)(nf + (size_t)src * 16);
        #pragma unroll
        for (int j = 0; j < 4; ++j) {
            float4 t = p[j];
            sf[4*j+0]=t.x; sf[4*j+1]=t.y; sf[4*j+2]=t.z; sf[4*j+3]=t.w;
        }
    }

    float* bp = blob + (size_t)slot * BSTRIDE;

    uint4 hku = make_uint4(bf2(hk[0],hk[1]), bf2(hk[2],hk[3]), bf2(hk[4],hk[5]), bf2(hk[6],hk[7]));
    *(uint4*)(bp + 0) = hku;
    *(float4*)(bp + 4) = ea;

    // v[u] = sf[u] * sum_h hv[h] * dot(ea, sv3t[u][h][:])  -> blob[8..23]
    #pragma unroll
    for (int j = 0; j < 4; ++j) {
        float o[4];
        #pragma unroll
        for (int cc = 0; cc < 4; ++cc) {
            int u = 4*j + cc;
            float t = 0.f;
            #pragma unroll
            for (int h = 0; h < 8; ++h) {
                const float4 r = *(const float4*)(&sv3t[u * 32 + h * 4]);
                t += hv[h] * (ea4[0]*r.x + ea4[1]*r.y + ea4[2]*r.z + ea4[3]*r.w);
            }
            o[cc] = sf[u] * t;
        }
        *(float4*)(bp + 8 + 4*j) = make_float4(o[0], o[1], o[2], o[3]);
    }
    bp[24] = __int_as_float(src);
}

// ---------------- B: fused logit + softmax-gather + output ----------------
// 256-thread block = 8 nodes, 16 groups of 16 lanes; group G: node ln=G>>1, sub=G&1.
// Each sub-group takes a contiguous half of its node's CSR range; 2-edge manual
// pipeline shares the R reads between the edge pair; partials combined via LDS.
constexpr int GN = 8;          // nodes per block
constexpr int RSTRIDE = 516;   // 512 + 4 pad

__global__ __launch_bounds__(256) void fused_gather_kernel(
    const int* __restrict__ offs,
    const float* __restrict__ blob,
    const float* __restrict__ nf, const float* __restrict__ qk,
    const float* __restrict__ fck_w3,
    const float* __restrict__ sc, const float* __restrict__ W_lin2,
    float* __restrict__ out)
{
    __shared__ float R[GN * RSTRIDE];   // 16.5 KB
    __shared__ float comb[GN][17];      // sub1 partials
    int tid = threadIdx.x;
    int nbase = blockIdx.x * GN;        // NN = 2500*8

    // block-cooperative R build: R[ln][h*64+u*4+v] = S3 * sum_c W3[h,u,v,c]*qk[n][c]
    constexpr float S3 = RS8 * 0.125f;  // fck_w3 scale * 1/sqrt(64)
    for (int idx = tid; idx < GN * 512; idx += 256) {
        int ln = idx >> 9;
        int j = idx & 511;              // j = h*64 + u*4 + v
        int h = j >> 6, uv = j & 63;
        const float4* w = (const float4*)(fck_w3 + h * 512 + uv * 8);
        float4 w0 = w[0], w1 = w[1];
        const float4* qp = (const float4*)(qk + (size_t)(nbase + ln) * 8);
        float4 q0 = qp[0], q1 = qp[1];
        float t = w0.x*q0.x + w0.y*q0.y + w0.z*q0.z + w0.w*q0.w
                + w1.x*q1.x + w1.y*q1.y + w1.z*q1.z + w1.w*q1.w;
        R[ln * RSTRIDE + j] = t * S3;
    }
    __syncthreads();

    int G = tid >> 4;          // group 0..15
    int ln = G >> 1;           // node 0..7
    int sub = G & 1;           // half 0/1
    int u = tid & 15;
    int wl = tid & 63;         // lane within wave
    int gbase = (G & 3) * 16;  // group's base lane within its wave
    int n = nbase + ln;

    int gs = (n == 0) ? 0 : offs[n - 1];
    int ge = offs[n];
    int cnt = ge - gs;
    int half = (cnt + 1) >> 1;
    int jb = gs + sub * half;
    int je = (sub == 0) ? (gs + half) : ge;

    const float* Rb = &R[ln * RSTRIDE];
    float accv = 0.f, accz = 0.f;

    int j = jb;
    for (; j + 1 < je; j += 2) {
        const float* bp0 = blob + (size_t)j * BSTRIDE;
        const float* bp1 = bp0 + BSTRIDE;
        uint4 hku0 = *(const uint4*)(bp0 + 0);
        uint4 hku1 = *(const uint4*)(bp1 + 0);
        float4 ea0 = *(const float4*)(bp0 + 4);
        float4 ea1 = *(const float4*)(bp1 + 4);
        int s0 = __float_as_int(bp0[24]);
        int s1 = __float_as_int(bp1[24]);
        float sfu0 = nf[(size_t)s0 * 16 + u];
        float sfu1 = nf[(size_t)s1 * 16 + u];

        float hk0[8], hk1[8];
        hk0[0]=bflo(hku0.x); hk0[1]=bfhi(hku0.x); hk0[2]=bflo(hku0.y); hk0[3]=bfhi(hku0.y);
        hk0[4]=bflo(hku0.z); hk0[5]=bfhi(hku0.z); hk0[6]=bflo(hku0.w); hk0[7]=bfhi(hku0.w);
        hk1[0]=bflo(hku1.x); hk1[1]=bfhi(hku1.x); hk1[2]=bflo(hku1.y); hk1[3]=bfhi(hku1.y);
        hk1[4]=bflo(hku1.z); hk1[5]=bfhi(hku1.z); hk1[6]=bflo(hku1.w); hk1[7]=bfhi(hku1.w);

        float xu0 = 0.f, xu1 = 0.f;
        #pragma unroll
        for (int h = 0; h < 8; ++h) {
            const float4 r = *(const float4*)(Rb + h * 64 + u * 4);   // shared by both edges
            float d0 = ea0.x*r.x + ea0.y*r.y + ea0.z*r.z + ea0.w*r.w;
            float d1 = ea1.x*r.x + ea1.y*r.y + ea1.z*r.z + ea1.w*r.w;
            xu0 += hk0[h] * d0;
            xu1 += hk1[h] * d1;
        }
        float px0 = sfu0 * xu0;
        float px1 = sfu1 * xu1;
        // interleaved 4-step in-group reductions
        px0 += __shfl_xor(px0, 1);  px1 += __shfl_xor(px1, 1);
        px0 += __shfl_xor(px0, 2);  px1 += __shfl_xor(px1, 2);
        px0 += __shfl_xor(px0, 4);  px1 += __shfl_xor(px1, 4);
        px0 += __shfl_xor(px0, 8);  px1 += __shfl_xor(px1, 8);
        float e0 = __expf(px0);
        float e1 = __expf(px1);
        accz += e0 + e1;
        accv += e0 * bp0[8 + u] + e1 * bp1[8 + u];
    }
    if (j < je) {
        const float* bp0 = blob + (size_t)j * BSTRIDE;
        uint4 hku0 = *(const uint4*)(bp0 + 0);
        float4 ea0 = *(const float4*)(bp0 + 4);
        int s0 = __float_as_int(bp0[24]);
        float sfu0 = nf[(size_t)s0 * 16 + u];
        float hk0[8];
        hk0[0]=bflo(hku0.x); hk0[1]=bfhi(hku0.x); hk0[2]=bflo(hku0.y); hk0[3]=bfhi(hku0.y);
        hk0[4]=bflo(hku0.z); hk0[5]=bfhi(hku0.z); hk0[6]=bflo(hku0.w); hk0[7]=bfhi(hku0.w);
        float xu0 = 0.f;
        #pragma unroll
        for (int h = 0; h < 8; ++h) {
            const float4 r = *(const float4*)(Rb + h * 64 + u * 4);
            xu0 += hk0[h] * (ea0.x*r.x + ea0.y*r.y + ea0.z*r.z + ea0.w*r.w);
        }
        float px0 = sfu0 * xu0;
        px0 += __shfl_xor(px0, 1);
        px0 += __shfl_xor(px0, 2);
        px0 += __shfl_xor(px0, 4);
        px0 += __shfl_xor(px0, 8);
        float e0 = __expf(px0);
        accz += e0;
        accv += e0 * bp0[8 + u];
    }

    // combine the two halves via LDS
    if (sub == 1) {
        comb[ln][u] = accv;
        if (u == 0) comb[ln][16] = accz;
    }
    __syncthreads();
    if (sub == 0) {
        accv += comb[ln][u];
        accz += comb[ln][16];

        float den = (accz == 0.f) ? 1.f : accz;
        float a = 0.25f * accv / den;                 // fold W_lin2's 1/sqrt(16)

        float t = sc[(size_t)n * 16 + u];
        #pragma unroll
        for (int uu = 0; uu < 16; ++uu) {
            float au = __shfl(a, gbase + uu);
            t += au * W_lin2[uu * 16 + u];            // 1 KB table, L1-resident
        }
        out[(size_t)n * 16 + u] = t;
    }
}

} // namespace

extern "C" void kernel_launch(void* const* d_in, const int* in_sizes, int n_in,
                              void* d_out, int out_size, void* d_ws, size_t ws_size,
                              hipStream_t stream)
{
    const float* node_input   = (const float*)d_in[0];
    const float* node_attr    = (const float*)d_in[1];
    const int*   edge_src     = (const int*)d_in[2];
    const int*   edge_dst     = (const int*)d_in[3];
    const float* edge_attr    = (const float*)d_in[4];
    const float* edge_scalars = (const float*)d_in[5];
    const float* W_sc   = (const float*)d_in[6];
    const float* W_lin1 = (const float*)d_in[7];
    const float* W_hq   = (const float*)d_in[8];
    const float* fck_w0 = (const float*)d_in[9];
    const float* fck_w1 = (const float*)d_in[10];
    const float* fck_w2 = (const float*)d_in[11];
    const float* fck_w3 = (const float*)d_in[12];
    const float* fcv_w0 = (const float*)d_in[13];
    const float* fcv_w1 = (const float*)d_in[14];
    const float* fcv_w2 = (const float*)d_in[15];
    const float* fcv_w3 = (const float*)d_in[16];
    const float* W_dot  = (const float*)d_in[17];
    const float* W_lin2 = (const float*)d_in[18];

    float* ws  = (float*)d_ws;
    float* nf  = ws;                       // NN*16
    float* qk  = nf  + (size_t)NN * 16;    // NN*8
    float* sc  = qk  + (size_t)NN * 8;     // NN*16
    float* blob = sc + (size_t)NN * 16;    // NE*32 (hk/ea/v/src, one 128B line per slot)
    int* counts = (int*)(blob + (size_t)NE * BSTRIDE);  // NN
    int* offs   = counts + NN;                          // NN

    hipMemsetAsync(counts, 0, (size_t)NN * sizeof(int), stream);

    const int EB = (NE + 255) / 256;   // 1563
    node_hist_kernel<<<EB, 256, 0, stream>>>(
        node_input, node_attr, edge_dst, W_sc, W_lin1, W_hq, W_dot, nf, qk, sc, counts);
    scan_kernel<<<1, 1024, 0, stream>>>(counts, offs);
    edge_mlp_kernel<<<EB, 256, 0, stream>>>(
        edge_src, edge_dst, edge_attr, edge_scalars, nf,
        fck_w0, fck_w1, fck_w2, fcv_w0, fcv_w1, fcv_w2, fcv_w3, offs, blob);
    fused_gather_kernel<<<NN / GN, 256, 0, stream>>>(
        offs, blob, nf, qk, fck_w3, sc, W_lin2, (float*)d_out);
}